// Round 1
// baseline (272.192 us; speedup 1.0000x reference)
//
#include <hip/hip_runtime.h>

typedef __bf16 bf16x8 __attribute__((ext_vector_type(8)));
typedef unsigned short u16x8 __attribute__((ext_vector_type(8)));
typedef float f32x4 __attribute__((ext_vector_type(4)));

#define BN_EPS 1e-5f

__device__ __forceinline__ unsigned short f2bf(float f) {
    union { float f; unsigned u; } x; x.f = f;
    unsigned r = x.u + 0x7fffu + ((x.u >> 16) & 1u);
    return (unsigned short)(r >> 16);
}

// ---------------- prepass: fold BN scale into pointwise weights (bf16), compute beta ----
__global__ void prep_kernel(const float* __restrict__ pw0, const float* __restrict__ pw1,
                            const float* __restrict__ w2,
                            const float* __restrict__ s0, const float* __restrict__ b0,
                            const float* __restrict__ m0, const float* __restrict__ v0,
                            const float* __restrict__ s1, const float* __restrict__ b1,
                            const float* __restrict__ m1, const float* __restrict__ v1,
                            const float* __restrict__ s2, const float* __restrict__ b2,
                            const float* __restrict__ m2, const float* __restrict__ v2,
                            unsigned short* __restrict__ wf0, unsigned short* __restrict__ wf1,
                            unsigned short* __restrict__ wf2, float* __restrict__ beta) {
    int o = blockIdx.x;     // 0..255
    int t = threadIdx.x;    // 0..255
    float inv0 = s0[o] * rsqrtf(v0[o] + BN_EPS);
    float inv1 = s1[o] * rsqrtf(v1[o] + BN_EPS);
    float inv2 = s2[o] * rsqrtf(v2[o] + BN_EPS);
    if (t == 0) {
        beta[0 * 256 + o] = b0[o] - m0[o] * inv0;
        beta[1 * 256 + o] = b1[o] - m1[o] * inv1;
        beta[2 * 256 + o] = b2[o] - m2[o] * inv2;
    }
    if (t < 128) {
        wf0[o * 128 + t] = f2bf(pw0[o * 128 + t] * inv0);
        wf1[o * 128 + t] = f2bf(pw1[o * 128 + t] * inv1);
    }
    wf2[o * 256 + t] = f2bf(w2[o * 256 + t] * inv2);
}

// ---------------- main fused kernel: 1 WG per (b,h) row, 8 waves ----------------------
// LDS B-tile: [64 px][512 K] bf16, pixel-major, XOR-swizzled (byte ^= (px&7)<<4).
// K layout: [0,128)=depthwise(rgb), [128,256)=depthwise(ir), [256,512)=raw x.
__global__ __launch_bounds__(512, 4)
void fused_kernel(const float* __restrict__ x,
                  const float* __restrict__ wts, const int* __restrict__ idx,
                  const float* __restrict__ dw0, const float* __restrict__ dw1,
                  const unsigned short* __restrict__ wf0,
                  const unsigned short* __restrict__ wf1,
                  const unsigned short* __restrict__ wf2,
                  const float* __restrict__ beta,
                  float* __restrict__ out) {
    __shared__ __align__(16) unsigned short lds[64 * 512];

    const int tid  = threadIdx.x;
    const int wave = tid >> 6;
    const int lane = tid & 63;
    const int b    = blockIdx.x >> 6;
    const int h    = blockIdx.x & 63;

    // per-batch expert coefficients (uniform per block)
    float c0 = 0.f, c1 = 0.f, c2 = 0.f;
#pragma unroll
    for (int t = 0; t < 2; ++t) {
        int e = idx[b * 2 + t];
        float w = wts[b * 2 + t];
        if (e == 0) c0 += w;
        else if (e == 1) c1 += w;
        else if (e == 2) c2 += w;
    }
    const float cc[3] = {c0, c1, c2};

    const long rowBase = (long)b * (256L * 4096L);   // x/out: channel stride 4096 floats

    // ---------- stage LDS ----------
    {
        const bool hm_ok = (h > 0), hp_ok = (h < 63);
        // depthwise rows: k in [wave*32, wave*32+32)
        for (int ch = 0; ch < 4; ++ch) {
            int k0 = wave * 32 + ch * 8;
            u16x8 pk;
#pragma unroll
            for (int j = 0; j < 8; ++j) {
                int k = k0 + j;                      // x channel == k for both halves
                const float* dwp = (k < 128) ? (dw0 + k * 9) : (dw1 + (k - 128) * 9);
                const float* xc = x + rowBase + (long)k * 4096 + h * 64 + lane;
                float vm = hm_ok ? xc[-64] : 0.f;
                float vc = xc[0];
                float vp = hp_ok ? xc[64] : 0.f;
                float lm = __shfl_up(vm, 1), lc = __shfl_up(vc, 1), lp = __shfl_up(vp, 1);
                float rm = __shfl_down(vm, 1), rc = __shfl_down(vc, 1), rp = __shfl_down(vp, 1);
                lm = (lane == 0) ? 0.f : lm;  lc = (lane == 0) ? 0.f : lc;  lp = (lane == 0) ? 0.f : lp;
                rm = (lane == 63) ? 0.f : rm; rc = (lane == 63) ? 0.f : rc; rp = (lane == 63) ? 0.f : rp;
                float y = dwp[0] * lm + dwp[1] * vm + dwp[2] * rm
                        + dwp[3] * lc + dwp[4] * vc + dwp[5] * rc
                        + dwp[6] * lp + dwp[7] * vp + dwp[8] * rp;
                pk[j] = f2bf(y);
            }
            int q = k0 >> 3;
            int off = lane * 1024 + ((q * 16) ^ ((lane & 7) << 4));
            *(u16x8*)((char*)lds + off) = pk;
        }
        // raw rows: channel c in [wave*32, wave*32+32) -> K row 256+c
        for (int ch = 0; ch < 4; ++ch) {
            int cb = wave * 32 + ch * 8;
            u16x8 pk;
#pragma unroll
            for (int j = 0; j < 8; ++j) {
                pk[j] = f2bf(x[rowBase + (long)(cb + j) * 4096 + h * 64 + lane]);
            }
            int q = 32 + (cb >> 3);
            int off = lane * 1024 + ((q * 16) ^ ((lane & 7) << 4));
            *(u16x8*)((char*)lds + off) = pk;
        }
    }
    __syncthreads();

    // ---------- GEMM phases ----------
    const int l15 = lane & 15;
    const int l4  = lane >> 4;

    f32x4 res[2][4];
#pragma unroll
    for (int ot = 0; ot < 2; ++ot)
#pragma unroll
        for (int tp = 0; tp < 4; ++tp)
            res[ot][tp] = (f32x4){0.f, 0.f, 0.f, 0.f};

    const unsigned short* Wp[3] = {wf0, wf1, wf2};
    const int KeA[3] = {128, 128, 256};
    const int kbA[3] = {0, 128, 256};

#pragma unroll
    for (int e = 0; e < 3; ++e) {
        const unsigned short* W = Wp[e];
        const int Ke = KeA[e];
        const int nk = Ke >> 5;

        f32x4 acc[2][4];
#pragma unroll
        for (int ot = 0; ot < 2; ++ot)
#pragma unroll
            for (int tp = 0; tp < 4; ++tp)
                acc[ot][tp] = (f32x4){0.f, 0.f, 0.f, 0.f};

        for (int kk = 0; kk < nk; ++kk) {
            bf16x8 a[2], bb[4];
#pragma unroll
            for (int ot = 0; ot < 2; ++ot) {
                int row = wave * 32 + ot * 16 + l15;
                a[ot] = *(const bf16x8*)((const char*)(W + row * Ke + kk * 32 + l4 * 8));
            }
#pragma unroll
            for (int tp = 0; tp < 4; ++tp) {
                int px = tp * 16 + l15;
                int q = (kbA[e] >> 3) + kk * 4 + l4;
                int off = px * 1024 + ((q * 16) ^ ((px & 7) << 4));
                bb[tp] = *(const bf16x8*)((char*)lds + off);
            }
#pragma unroll
            for (int ot = 0; ot < 2; ++ot)
#pragma unroll
                for (int tp = 0; tp < 4; ++tp)
                    acc[ot][tp] = __builtin_amdgcn_mfma_f32_16x16x32_bf16(a[ot], bb[tp], acc[ot][tp], 0, 0, 0);
        }

        // epilogue: BN shift + SiLU + weighted accumulate
        const float ce = cc[e];
        const float* bp = beta + e * 256;
#pragma unroll
        for (int ot = 0; ot < 2; ++ot) {
#pragma unroll
            for (int j = 0; j < 4; ++j) {
                int o = wave * 32 + ot * 16 + l4 * 4 + j;
                float bet = bp[o];
#pragma unroll
                for (int tp = 0; tp < 4; ++tp) {
                    float v = acc[ot][tp][j] + bet;
                    float sig = __builtin_amdgcn_rcpf(1.f + __expf(-v));
                    res[ot][tp][j] += ce * (v * sig);
                }
            }
        }
    }

    // ---------- store ----------
    const long outBase = rowBase + h * 64;
#pragma unroll
    for (int ot = 0; ot < 2; ++ot) {
#pragma unroll
        for (int j = 0; j < 4; ++j) {
            int o = wave * 32 + ot * 16 + l4 * 4 + j;
            float* op = out + outBase + (long)o * 4096;
#pragma unroll
            for (int tp = 0; tp < 4; ++tp)
                op[tp * 16 + l15] = res[ot][tp][j];
        }
    }
}

extern "C" void kernel_launch(void* const* d_in, const int* in_sizes, int n_in,
                              void* d_out, int out_size, void* d_ws, size_t ws_size,
                              hipStream_t stream) {
    const float* x    = (const float*)d_in[0];
    const float* wts  = (const float*)d_in[1];
    const int*   idx  = (const int*)d_in[2];
    const float* dw0  = (const float*)d_in[3];
    const float* pw0  = (const float*)d_in[4];
    const float* s0   = (const float*)d_in[5];
    const float* b0   = (const float*)d_in[6];
    const float* m0   = (const float*)d_in[7];
    const float* v0   = (const float*)d_in[8];
    const float* dw1  = (const float*)d_in[9];
    const float* pw1  = (const float*)d_in[10];
    const float* s1   = (const float*)d_in[11];
    const float* b1   = (const float*)d_in[12];
    const float* m1   = (const float*)d_in[13];
    const float* v1   = (const float*)d_in[14];
    const float* w2   = (const float*)d_in[15];
    const float* s2   = (const float*)d_in[16];
    const float* b2   = (const float*)d_in[17];
    const float* m2   = (const float*)d_in[18];
    const float* v2   = (const float*)d_in[19];

    unsigned short* wf0  = (unsigned short*)d_ws;
    unsigned short* wf1  = wf0 + 256 * 128;
    unsigned short* wf2  = wf1 + 256 * 128;
    float*          beta = (float*)(wf2 + 256 * 256);

    prep_kernel<<<256, 256, 0, stream>>>(pw0, pw1, w2,
                                         s0, b0, m0, v0,
                                         s1, b1, m1, v1,
                                         s2, b2, m2, v2,
                                         wf0, wf1, wf2, beta);

    fused_kernel<<<2048, 512, 0, stream>>>(x, wts, idx, dw0, dw1,
                                           wf0, wf1, wf2, beta, (float*)d_out);
}

// Round 2
// 164.815 us; speedup vs baseline: 1.6515x; 1.6515x over previous
//
#include <hip/hip_runtime.h>

typedef __bf16 bf16x8 __attribute__((ext_vector_type(8)));
typedef float f32x4 __attribute__((ext_vector_type(4)));

#define BN_EPS 1e-5f

__device__ __forceinline__ unsigned short f2bf(float f) {
    union { float f; unsigned u; } x; x.f = f;
    unsigned r = x.u + 0x7fffu + ((x.u >> 16) & 1u);
    return (unsigned short)(r >> 16);
}

__device__ __forceinline__ unsigned pk_bf16(float lo, float hi) {
    unsigned r;
    asm("v_cvt_pk_bf16_f32 %0, %1, %2" : "=v"(r) : "v"(lo), "v"(hi));
    return r;
}

// ---------------- prepass: fold BN scale into pointwise weights (bf16), compute beta ----
__global__ void prep_kernel(const float* __restrict__ pw0, const float* __restrict__ pw1,
                            const float* __restrict__ w2,
                            const float* __restrict__ s0, const float* __restrict__ b0,
                            const float* __restrict__ m0, const float* __restrict__ v0,
                            const float* __restrict__ s1, const float* __restrict__ b1,
                            const float* __restrict__ m1, const float* __restrict__ v1,
                            const float* __restrict__ s2, const float* __restrict__ b2,
                            const float* __restrict__ m2, const float* __restrict__ v2,
                            unsigned short* __restrict__ wf0, unsigned short* __restrict__ wf1,
                            unsigned short* __restrict__ wf2, float* __restrict__ beta) {
    int o = blockIdx.x;     // 0..255
    int t = threadIdx.x;    // 0..255
    float inv0 = s0[o] * rsqrtf(v0[o] + BN_EPS);
    float inv1 = s1[o] * rsqrtf(v1[o] + BN_EPS);
    float inv2 = s2[o] * rsqrtf(v2[o] + BN_EPS);
    if (t == 0) {
        beta[0 * 256 + o] = b0[o] - m0[o] * inv0;
        beta[1 * 256 + o] = b1[o] - m1[o] * inv1;
        beta[2 * 256 + o] = b2[o] - m2[o] * inv2;
    }
    if (t < 128) {
        wf0[o * 128 + t] = f2bf(pw0[o * 128 + t] * inv0);
        wf1[o * 128 + t] = f2bf(pw1[o * 128 + t] * inv1);
    }
    wf2[o * 256 + t] = f2bf(w2[o * 256 + t] * inv2);
}

// ---------------- main fused kernel: 1 WG per (b,h) row, 8 waves ----------------------
// LDS B-tile: [64 px][512 K] bf16, pixel-major, XOR-swizzled (byte ^= (px&7)<<4).
// K layout: [0,128)=depthwise(rgb), [128,256)=depthwise(ir), [256,512)=raw x.
__global__ __launch_bounds__(512, 4)
void fused_kernel(const float* __restrict__ x,
                  const float* __restrict__ wts, const int* __restrict__ idx,
                  const float* __restrict__ dw0, const float* __restrict__ dw1,
                  const unsigned short* __restrict__ wf0,
                  const unsigned short* __restrict__ wf1,
                  const unsigned short* __restrict__ wf2,
                  const float* __restrict__ beta,
                  float* __restrict__ out) {
    __shared__ __align__(16) char lds[64 * 1024];

    const int tid  = threadIdx.x;
    const int wave = tid >> 6;
    const int lane = tid & 63;

    // XCD-aware swizzle: consecutive h (same b) stay on one XCD for L2 reuse.
    const int bid = blockIdx.x;
    const int nb  = ((bid & 7) << 8) | (bid >> 3);   // 2048 = 8 * 256, bijective
    const int b   = nb >> 6;
    const int h   = nb & 63;

    // per-batch expert coefficients (uniform per block)
    float c0 = 0.f, c1 = 0.f, c2 = 0.f;
#pragma unroll
    for (int t = 0; t < 2; ++t) {
        int e = idx[b * 2 + t];
        float w = wts[b * 2 + t];
        if (e == 0) c0 += w;
        else if (e == 1) c1 += w;
        else if (e == 2) c2 += w;
    }
    const float cc[3] = {c0, c1, c2};

    const long rowBase = (long)b * 1048576L;         // x/out: batch stride 256*4096 floats

    // ---------- stage LDS (depthwise + raw merged) ----------
    {
        const int g   = lane >> 2;                   // px-group 0..15 (4 px each)
        const int kq  = lane & 3;                    // k-quad within 16-k chunk
        const int px0 = g * 4;
        const float* xb = x + rowBase + h * 64 + px0;
        const bool hm = (h > 0), hp = (h < 63);

#pragma unroll
        for (int i = 0; i < 2; ++i) {
            const int k0 = wave * 32 + i * 16 + kq * 4;   // 4 k's: k0..k0+3
            unsigned dw_p[2][4], rw_p[2][4];
#pragma unroll
            for (int pr = 0; pr < 2; ++pr) {
                float y[2][4]; float rv[2][4];
#pragma unroll
                for (int k2 = 0; k2 < 2; ++k2) {
                    const int k = k0 + pr * 2 + k2;
                    const float* dwp = (k < 128) ? (dw0 + k * 9) : (dw1 + (k - 128) * 9);
                    const float* xc = xb + (long)k * 4096;
                    float4 rm = hm ? *(const float4*)(xc - 64) : make_float4(0.f, 0.f, 0.f, 0.f);
                    float4 rc = *(const float4*)(xc);
                    float4 rp = hp ? *(const float4*)(xc + 64) : make_float4(0.f, 0.f, 0.f, 0.f);
                    float lm = __shfl_up(rm.w, 4), lc = __shfl_up(rc.w, 4), lp = __shfl_up(rp.w, 4);
                    float Rm = __shfl_down(rm.x, 4), Rc = __shfl_down(rc.x, 4), Rp = __shfl_down(rp.x, 4);
                    if (g == 0)  { lm = 0.f; lc = 0.f; lp = 0.f; }
                    if (g == 15) { Rm = 0.f; Rc = 0.f; Rp = 0.f; }
                    const float w0 = dwp[0], w1 = dwp[1], w2 = dwp[2];
                    const float w3 = dwp[3], w4 = dwp[4], w5 = dwp[5];
                    const float w6 = dwp[6], w7 = dwp[7], w8 = dwp[8];
                    y[k2][0] = w0*lm   + w1*rm.x + w2*rm.y + w3*lc   + w4*rc.x + w5*rc.y + w6*lp   + w7*rp.x + w8*rp.y;
                    y[k2][1] = w0*rm.x + w1*rm.y + w2*rm.z + w3*rc.x + w4*rc.y + w5*rc.z + w6*rp.x + w7*rp.y + w8*rp.z;
                    y[k2][2] = w0*rm.y + w1*rm.z + w2*rm.w + w3*rc.y + w4*rc.z + w5*rc.w + w6*rp.y + w7*rp.z + w8*rp.w;
                    y[k2][3] = w0*rm.z + w1*rm.w + w2*Rm   + w3*rc.z + w4*rc.w + w5*Rc   + w6*rp.z + w7*rp.w + w8*Rp;
                    rv[k2][0] = rc.x; rv[k2][1] = rc.y; rv[k2][2] = rc.z; rv[k2][3] = rc.w;
                }
#pragma unroll
                for (int j = 0; j < 4; ++j) {
                    dw_p[pr][j] = pk_bf16(y[0][j], y[1][j]);
                    rw_p[pr][j] = pk_bf16(rv[0][j], rv[1][j]);
                }
            }
            const int qd  = (k0 >> 3) * 16;          // dw 16-B column byte offset
            const int qr  = qd + 32 * 16;            // raw rows start at K=256 -> col +32
            const int sub = (k0 & 4) * 2;            // 0 or 8 within column
#pragma unroll
            for (int j = 0; j < 4; ++j) {
                const int px = px0 + j;
                const int sw = (px & 7) << 4;
                *(uint2*)(lds + px * 1024 + (qd ^ sw) + sub) = make_uint2(dw_p[0][j], dw_p[1][j]);
                *(uint2*)(lds + px * 1024 + (qr ^ sw) + sub) = make_uint2(rw_p[0][j], rw_p[1][j]);
            }
        }
    }

    // prefetch e=0 kk=0 A-fragments before the barrier (independent of LDS)
    const int l15 = lane & 15;
    const int l4  = lane >> 4;
    bf16x8 pre0[2];
#pragma unroll
    for (int ot = 0; ot < 2; ++ot)
        pre0[ot] = *(const bf16x8*)(wf0 + (wave * 32 + ot * 16 + l15) * 128 + l4 * 8);

    __syncthreads();

    // ---------- GEMM phases ----------
    f32x4 res[2][4];
#pragma unroll
    for (int ot = 0; ot < 2; ++ot)
#pragma unroll
        for (int tp = 0; tp < 4; ++tp)
            res[ot][tp] = (f32x4){0.f, 0.f, 0.f, 0.f};

    const unsigned short* Wp[3] = {wf0, wf1, wf2};
    const int KeA[3] = {128, 128, 256};
    const int kbA[3] = {0, 128, 256};

    int pxv[4], swv[4];
#pragma unroll
    for (int tp = 0; tp < 4; ++tp) {
        pxv[tp] = tp * 16 + l15;
        swv[tp] = (pxv[tp] & 7) << 4;
    }

#pragma unroll
    for (int e = 0; e < 3; ++e) {
        const unsigned short* W = Wp[e];
        const int Ke = KeA[e];
        const int nk = Ke >> 5;
        const int qb = (kbA[e] >> 3) * 16;           // byte column base

        f32x4 acc[2][4];
#pragma unroll
        for (int ot = 0; ot < 2; ++ot)
#pragma unroll
            for (int tp = 0; tp < 4; ++tp)
                acc[ot][tp] = (f32x4){0.f, 0.f, 0.f, 0.f};

        const unsigned short* wb = W + (wave * 32 + l15) * Ke + l4 * 8;

        bf16x8 aC[2], bC[4];
        if (e == 0) { aC[0] = pre0[0]; aC[1] = pre0[1]; }
        else {
#pragma unroll
            for (int ot = 0; ot < 2; ++ot) aC[ot] = *(const bf16x8*)(wb + ot * 16 * Ke);
        }
#pragma unroll
        for (int tp = 0; tp < 4; ++tp)
            bC[tp] = *(const bf16x8*)(lds + pxv[tp] * 1024 + ((qb + l4 * 16) ^ swv[tp]));

#pragma unroll
        for (int kk = 0; kk < 8; ++kk) {
            if (kk >= nk) break;
            bf16x8 aN[2], bN[4];
            if (kk + 1 < nk) {
#pragma unroll
                for (int ot = 0; ot < 2; ++ot)
                    aN[ot] = *(const bf16x8*)(wb + ot * 16 * Ke + (kk + 1) * 32);
#pragma unroll
                for (int tp = 0; tp < 4; ++tp)
                    bN[tp] = *(const bf16x8*)(lds + pxv[tp] * 1024 + ((qb + (kk + 1) * 64 + l4 * 16) ^ swv[tp]));
            }
#pragma unroll
            for (int ot = 0; ot < 2; ++ot)
#pragma unroll
                for (int tp = 0; tp < 4; ++tp)
                    acc[ot][tp] = __builtin_amdgcn_mfma_f32_16x16x32_bf16(aC[ot], bC[tp], acc[ot][tp], 0, 0, 0);
            if (kk + 1 < nk) {
#pragma unroll
                for (int ot = 0; ot < 2; ++ot) aC[ot] = aN[ot];
#pragma unroll
                for (int tp = 0; tp < 4; ++tp) bC[tp] = bN[tp];
            }
        }

        // epilogue: BN shift + SiLU + weighted accumulate
        const float ce = cc[e];
        const float* bp = beta + e * 256;
#pragma unroll
        for (int ot = 0; ot < 2; ++ot) {
#pragma unroll
            for (int j = 0; j < 4; ++j) {
                int o = wave * 32 + ot * 16 + l4 * 4 + j;
                float bet = bp[o];
#pragma unroll
                for (int tp = 0; tp < 4; ++tp) {
                    float v = acc[ot][tp][j] + bet;
                    float sig = __builtin_amdgcn_rcpf(1.f + __expf(-v));
                    res[ot][tp][j] += ce * (v * sig);
                }
            }
        }
    }

    // ---------- store: transpose through LDS, 256-B coalesced lines ----------
    float* lds_f = (float*)lds;
    const long outB = rowBase + h * 64;
    __syncthreads();                                  // all waves done reading B-tile
#pragma unroll
    for (int r = 0; r < 2; ++r) {
        if ((wave >> 2) == r) {
#pragma unroll
            for (int ot = 0; ot < 2; ++ot)
#pragma unroll
                for (int j = 0; j < 4; ++j) {
                    int o = wave * 32 + ot * 16 + l4 * 4 + j;
#pragma unroll
                    for (int tp = 0; tp < 4; ++tp)
                        lds_f[(o & 127) * 68 + tp * 16 + l15] = res[ot][tp][j];
                }
        }
        __syncthreads();
        {
            const int row = tid >> 4;                 // 0..31
            const int col = (tid & 15) * 4;           // float index
#pragma unroll
            for (int rr = 0; rr < 4; ++rr) {
                int lr = row + rr * 32;               // 0..127
                float4 v = *(float4*)&lds_f[lr * 68 + col];
                *(float4*)(out + outB + (long)(r * 128 + lr) * 4096 + col) = v;
            }
        }
        __syncthreads();
    }
}

extern "C" void kernel_launch(void* const* d_in, const int* in_sizes, int n_in,
                              void* d_out, int out_size, void* d_ws, size_t ws_size,
                              hipStream_t stream) {
    const float* x    = (const float*)d_in[0];
    const float* wts  = (const float*)d_in[1];
    const int*   idx  = (const int*)d_in[2];
    const float* dw0  = (const float*)d_in[3];
    const float* pw0  = (const float*)d_in[4];
    const float* s0   = (const float*)d_in[5];
    const float* b0   = (const float*)d_in[6];
    const float* m0   = (const float*)d_in[7];
    const float* v0   = (const float*)d_in[8];
    const float* dw1  = (const float*)d_in[9];
    const float* pw1  = (const float*)d_in[10];
    const float* s1   = (const float*)d_in[11];
    const float* b1   = (const float*)d_in[12];
    const float* m1   = (const float*)d_in[13];
    const float* v1   = (const float*)d_in[14];
    const float* w2   = (const float*)d_in[15];
    const float* s2   = (const float*)d_in[16];
    const float* b2   = (const float*)d_in[17];
    const float* m2   = (const float*)d_in[18];
    const float* v2   = (const float*)d_in[19];

    unsigned short* wf0  = (unsigned short*)d_ws;
    unsigned short* wf1  = wf0 + 256 * 128;
    unsigned short* wf2  = wf1 + 256 * 128;
    float*          beta = (float*)(wf2 + 256 * 256);

    prep_kernel<<<256, 256, 0, stream>>>(pw0, pw1, w2,
                                         s0, b0, m0, v0,
                                         s1, b1, m1, v1,
                                         s2, b2, m2, v2,
                                         wf0, wf1, wf2, beta);

    fused_kernel<<<2048, 512, 0, stream>>>(x, wts, idx, dw0, dw1,
                                           wf0, wf1, wf2, beta, (float*)d_out);
}